// Round 1
// baseline (517.554 us; speedup 1.0000x reference)
//
#include <hip/hip_runtime.h>
#include <hip/hip_fp16.h>

#define N_INST 64
#define T_DIM  4096
#define DI     128
#define DH     256
#define DO     128
#define RPB    512   // rows per block
#define BT     64    // rows per subtile

typedef _Float16 f16x8 __attribute__((ext_vector_type(8)));
typedef _Float16 f16x4 __attribute__((ext_vector_type(4)));
typedef float    f32x4 __attribute__((ext_vector_type(4)));

// Fused per-instance MLP: out = silu(X@W1 + b1) @ W2 + b2
// Block: 256 thr (4 waves). Wave w owns GEMM1 cols [64w,64w+64), GEMM2 cols [32w,32w+32).
// Weights live in registers (fp16 B-frags) for the whole block; X and H staged in
// XOR-swizzled LDS; fp32 accumulate in MFMA.
__global__ __launch_bounds__(256, 2)
void pmlp_kernel(const float* __restrict__ X, const float* __restrict__ W1,
                 const float* __restrict__ B1, const float* __restrict__ W2,
                 const float* __restrict__ B2, float* __restrict__ OUT) {
  __shared__ _Float16 Xs[BT * DI];  // 16 KB, swizzled rows of 256B
  __shared__ _Float16 Hs[BT * DH];  // 32 KB, swizzled rows of 512B

  const int n    = blockIdx.y;
  const int row0 = blockIdx.x * RPB;
  const int tid  = threadIdx.x;
  const int w    = tid >> 6;   // wave 0..3
  const int l    = tid & 63;
  const int l16  = l & 15;
  const int lk   = l >> 4;     // 0..3

  const float* W1n = W1 + (size_t)n * DI * DH;
  const float* W2n = W2 + (size_t)n * DH * DO;

  // ---- hoist weights into registers as MFMA B-fragments ----
  // B-frag layout for mfma_f32_16x16x32_f16: col = lane&15, k = (lane>>4)*8 + j
  f16x8 w1f[4][4];  // [ntile][kiter]
  #pragma unroll
  for (int nt = 0; nt < 4; ++nt) {
    const int col = w * 64 + nt * 16 + l16;
    #pragma unroll
    for (int kit = 0; kit < 4; ++kit) {
      const int k0 = kit * 32 + lk * 8;
      f16x8 f;
      #pragma unroll
      for (int j = 0; j < 8; ++j) f[j] = (_Float16)W1n[(size_t)(k0 + j) * DH + col];
      w1f[nt][kit] = f;
    }
  }
  f16x8 w2f[2][8];  // [ntile][kiter]
  #pragma unroll
  for (int nt = 0; nt < 2; ++nt) {
    const int col = w * 32 + nt * 16 + l16;
    #pragma unroll
    for (int kit = 0; kit < 8; ++kit) {
      const int k0 = kit * 32 + lk * 8;
      f16x8 f;
      #pragma unroll
      for (int j = 0; j < 8; ++j) f[j] = (_Float16)W2n[(size_t)(k0 + j) * DO + col];
      w2f[nt][kit] = f;
    }
  }
  float b1v[4], b2v[2];
  #pragma unroll
  for (int nt = 0; nt < 4; ++nt) b1v[nt] = B1[n * DH + w * 64 + nt * 16 + l16];
  #pragma unroll
  for (int nt = 0; nt < 2; ++nt) b2v[nt] = B2[n * DO + w * 32 + nt * 16 + l16];

  for (int st = 0; st < RPB / BT; ++st) {
    const int rbase = row0 + st * BT;

    // ---- stage X subtile: 64x128 fp32 -> fp16, swizzled ----
    {
      const float* Xp = X + ((size_t)n * T_DIM + rbase) * DI;
      const int c  = tid & 31;   // 16B chunk in row (32 chunks of 4 fp32)
      const int r0 = tid >> 5;   // 0..7
      #pragma unroll
      for (int i = 0; i < 8; ++i) {
        const int r = r0 + i * 8;
        const float4 v = *(const float4*)(Xp + (size_t)r * DI + c * 4);
        f16x4 h;
        h[0] = (_Float16)v.x; h[1] = (_Float16)v.y;
        h[2] = (_Float16)v.z; h[3] = (_Float16)v.w;
        int byte = r * 256 + c * 8;
        byte ^= (r & 7) << 4;
        *(f16x4*)((char*)Xs + byte) = h;
      }
    }
    __syncthreads();

    // ---- GEMM1: H = silu(Xs @ W1 + b1), wave cols [64w, 64w+64) ----
    f32x4 acc1[4][4];  // [mtile][ntile]
    #pragma unroll
    for (int m = 0; m < 4; ++m)
      #pragma unroll
      for (int nt = 0; nt < 4; ++nt) acc1[m][nt] = (f32x4){0.f, 0.f, 0.f, 0.f};

    #pragma unroll
    for (int kit = 0; kit < 4; ++kit) {
      f16x8 a[4];
      #pragma unroll
      for (int m = 0; m < 4; ++m) {
        const int row = m * 16 + l16;
        int byte = row * 256 + kit * 64 + lk * 16;
        byte ^= (row & 7) << 4;
        a[m] = *(const f16x8*)((const char*)Xs + byte);
      }
      #pragma unroll
      for (int m = 0; m < 4; ++m)
        #pragma unroll
        for (int nt = 0; nt < 4; ++nt)
          acc1[m][nt] = __builtin_amdgcn_mfma_f32_16x16x32_f16(a[m], w1f[nt][kit], acc1[m][nt], 0, 0, 0);
    }

    // bias + SiLU + write Hs (fp16, swizzled). D-frag: col=lane&15, row=(lane>>4)*4+reg
    #pragma unroll
    for (int m = 0; m < 4; ++m) {
      #pragma unroll
      for (int nt = 0; nt < 4; ++nt) {
        const int col = w * 64 + nt * 16 + l16;
        #pragma unroll
        for (int r = 0; r < 4; ++r) {
          const float z = acc1[m][nt][r] + b1v[nt];
          const float hv = z / (1.0f + __expf(-z));
          const int row = m * 16 + lk * 4 + r;
          int byte = row * 512 + col * 2;
          byte ^= (row & 7) << 4;
          *(_Float16*)((char*)Hs + byte) = (_Float16)hv;
        }
      }
    }
    __syncthreads();

    // ---- GEMM2: OUT = Hs @ W2 + b2, wave cols [32w, 32w+32) ----
    f32x4 acc2[4][2];
    #pragma unroll
    for (int m = 0; m < 4; ++m)
      #pragma unroll
      for (int nt = 0; nt < 2; ++nt) acc2[m][nt] = (f32x4){0.f, 0.f, 0.f, 0.f};

    #pragma unroll
    for (int kit = 0; kit < 8; ++kit) {
      f16x8 a[4];
      #pragma unroll
      for (int m = 0; m < 4; ++m) {
        const int row = m * 16 + l16;
        int byte = row * 512 + kit * 64 + lk * 16;
        byte ^= (row & 7) << 4;
        a[m] = *(const f16x8*)((const char*)Hs + byte);
      }
      #pragma unroll
      for (int m = 0; m < 4; ++m)
        #pragma unroll
        for (int nt = 0; nt < 2; ++nt)
          acc2[m][nt] = __builtin_amdgcn_mfma_f32_16x16x32_f16(a[m], w2f[nt][kit], acc2[m][nt], 0, 0, 0);
    }

    // epilogue: + b2, store fp32
    float* Op = OUT + ((size_t)n * T_DIM + rbase) * DO;
    #pragma unroll
    for (int m = 0; m < 4; ++m) {
      #pragma unroll
      for (int nt = 0; nt < 2; ++nt) {
        const int col = w * 32 + nt * 16 + l16;
        #pragma unroll
        for (int r = 0; r < 4; ++r) {
          const int row = m * 16 + lk * 4 + r;
          Op[(size_t)row * DO + col] = acc2[m][nt][r] + b2v[nt];
        }
      }
    }
    // no trailing barrier needed: next stage writes Xs, whose last reader
    // (GEMM1) is already fenced by the mid-subtile __syncthreads
  }
}

extern "C" void kernel_launch(void* const* d_in, const int* in_sizes, int n_in,
                              void* d_out, int out_size, void* d_ws, size_t ws_size,
                              hipStream_t stream) {
  const float* X  = (const float*)d_in[0];
  const float* W1 = (const float*)d_in[1];
  const float* B1 = (const float*)d_in[2];
  const float* W2 = (const float*)d_in[3];
  const float* B2 = (const float*)d_in[4];
  float* OUT = (float*)d_out;

  dim3 grid(T_DIM / RPB, N_INST);  // 8 x 64 = 512 blocks
  pmlp_kernel<<<grid, dim3(256), 0, stream>>>(X, W1, B1, W2, B2, OUT);
}

// Round 2
// 381.653 us; speedup vs baseline: 1.3561x; 1.3561x over previous
//
#include <hip/hip_runtime.h>
#include <hip/hip_fp16.h>

#define N_INST 64
#define T_DIM  4096
#define DI     128
#define DH     256
#define DO     128
#define RPB    512          // rows per block
#define BT     32           // tokens per subtile
#define NST    (RPB / BT)   // 16 subtiles

typedef _Float16 f16x8 __attribute__((ext_vector_type(8)));
typedef _Float16 f16x4 __attribute__((ext_vector_type(4)));
typedef float    f32x4 __attribute__((ext_vector_type(4)));

// Fused per-instance MLP: OUT = silu(X@W1 + b1) @ W2 + b2, fp16 MFMA, fp32 accum.
// Grid 512 blocks (all resident, 2/CU). XCD-pinned: instance n -> XCD n%8 so the
// 8 blocks of an instance share one L2 (weights fetched from HBM ~once: 17 MB).
// Weights persist in registers (fragments), loaded coalesced via a 32KB LDS bounce.
// Swapped-operand MFMA (weights as A) gives transposed D-frags -> vectorized
// ds_write_b64 for H and full-line dwordx4 OUT stores.
__global__ __launch_bounds__(256, 2)
void pmlp_kernel(const float* __restrict__ X, const float* __restrict__ W1,
                 const float* __restrict__ B1, const float* __restrict__ W2,
                 const float* __restrict__ B2, float* __restrict__ OUT) {
  __shared__ __align__(16) char smem[32768];
  _Float16* Xs = (_Float16*)smem;           // 8KB  [32 tok][128 k] fp16, swizzled
  _Float16* Hs = (_Float16*)(smem + 8192);  // 16KB [32 tok][256 h] fp16, swizzled
  _Float16* Ws = (_Float16*)smem;           // 32KB preload scratch (pre-loop only)

  const int bid = blockIdx.x;
  const int g     = bid & 7;             // XCD (dispatch round-robin heuristic)
  const int j     = bid >> 3;            // 0..63
  const int n     = ((j & 7) << 3) | g;  // instance, pinned: n%8 == XCD
  const int chunk = j >> 3;              // 0..7 row-chunk of this instance
  const int row0  = chunk * RPB;

  const int tid = threadIdx.x;
  const int w   = tid >> 6;   // wave 0..3
  const int l   = tid & 63;
  const int l16 = l & 15;
  const int lk  = l >> 4;     // 0..3

  const float* W1n = W1 + (size_t)n * DI * DH;
  const float* W2n = W2 + (size_t)n * DH * DO;

  // ---- coalesced weight preload via LDS bounce, fragments into registers ----
  // frag layout (A/B symmetric): element j at (k = kit*32 + lk*8 + j, col = base+l16)
  f16x8 w1f[4][4];  // wave owns hcols [64w, 64w+64): nt tiles x kit
  f16x8 w2f[2][8];  // wave owns ocols [32w, 32w+32)

  #pragma unroll 1
  for (int c = 0; c < 2; ++c) {  // W1: 2 chunks of 64 k-rows (16384 floats)
    const float* src = W1n + (size_t)c * 64 * DH;
    #pragma unroll
    for (int i = 0; i < 16; ++i) {
      const int f4 = i * 256 + tid;
      const float4 v = *(const float4*)(src + (size_t)f4 * 4);
      f16x4 h;
      h[0] = (_Float16)v.x; h[1] = (_Float16)v.y;
      h[2] = (_Float16)v.z; h[3] = (_Float16)v.w;
      *(f16x4*)((char*)Ws + f4 * 8) = h;
    }
    __syncthreads();
    #pragma unroll
    for (int kk = 0; kk < 2; ++kk)
      #pragma unroll
      for (int nt = 0; nt < 4; ++nt) {
        const int col = w * 64 + nt * 16 + l16;
        f16x8 f;
        #pragma unroll
        for (int jj = 0; jj < 8; ++jj)
          f[jj] = Ws[(kk * 32 + lk * 8 + jj) * DH + col];
        w1f[nt][c * 2 + kk] = f;
      }
    __syncthreads();
  }
  #pragma unroll 1
  for (int c = 0; c < 2; ++c) {  // W2: 2 chunks of 128 k-rows (16384 floats)
    const float* src = W2n + (size_t)c * 128 * DO;
    #pragma unroll
    for (int i = 0; i < 16; ++i) {
      const int f4 = i * 256 + tid;
      const float4 v = *(const float4*)(src + (size_t)f4 * 4);
      f16x4 h;
      h[0] = (_Float16)v.x; h[1] = (_Float16)v.y;
      h[2] = (_Float16)v.z; h[3] = (_Float16)v.w;
      *(f16x4*)((char*)Ws + f4 * 8) = h;
    }
    __syncthreads();
    #pragma unroll
    for (int kk = 0; kk < 4; ++kk)
      #pragma unroll
      for (int nt = 0; nt < 2; ++nt) {
        const int col = w * 32 + nt * 16 + l16;
        f16x8 f;
        #pragma unroll
        for (int jj = 0; jj < 8; ++jj)
          f[jj] = Ws[(kk * 32 + lk * 8 + jj) * DO + col];
        w2f[nt][c * 4 + kk] = f;
      }
    __syncthreads();
  }

  // biases, indexed by the transposed D-frag: rows (lane>>4)*4+r are COLUMNS now
  f32x4 b1v[4], b2v[2];
  #pragma unroll
  for (int nt = 0; nt < 4; ++nt)
    b1v[nt] = *(const f32x4*)(B1 + n * DH + w * 64 + nt * 16 + lk * 4);
  #pragma unroll
  for (int nt = 0; nt < 2; ++nt)
    b2v[nt] = *(const f32x4*)(B2 + n * DO + w * 32 + nt * 16 + lk * 4);

  const float* Xbase = X + ((size_t)n * T_DIM + row0) * DI;
  float*       Obase = OUT + ((size_t)n * T_DIM + row0) * DO;

  // prologue: prefetch subtile 0 (1024 float4 per subtile, 4 per thread)
  float4 xr[4];
  #pragma unroll
  for (int i = 0; i < 4; ++i)
    xr[i] = *(const float4*)(Xbase + (size_t)(i * 256 + tid) * 4);

  #pragma unroll 1
  for (int st = 0; st < NST; ++st) {
    // ---- write Xs(st) from prefetch regs (fp32 -> fp16, swizzled) ----
    #pragma unroll
    for (int i = 0; i < 4; ++i) {
      const int f4 = i * 256 + tid;
      const int r = f4 >> 5, c4 = f4 & 31;
      f16x4 h;
      h[0] = (_Float16)xr[i].x; h[1] = (_Float16)xr[i].y;
      h[2] = (_Float16)xr[i].z; h[3] = (_Float16)xr[i].w;
      int byte = r * 256 + c4 * 8;
      byte ^= (r & 7) << 4;
      *(f16x4*)((char*)Xs + byte) = h;
    }
    __syncthreads();

    // ---- GEMM1 (swapped): D = W1tile^T * X^T, lane&15 = token ----
    f32x4 acc1[2][4];
    #pragma unroll
    for (int m = 0; m < 2; ++m)
      #pragma unroll
      for (int nt = 0; nt < 4; ++nt) acc1[m][nt] = (f32x4){0.f, 0.f, 0.f, 0.f};

    #pragma unroll
    for (int kit = 0; kit < 4; ++kit) {
      f16x8 a[2];
      #pragma unroll
      for (int m = 0; m < 2; ++m) {
        const int r = m * 16 + l16;
        int byte = r * 256 + kit * 64 + lk * 16;
        byte ^= (r & 7) << 4;
        a[m] = *(const f16x8*)((const char*)Xs + byte);
      }
      #pragma unroll
      for (int m = 0; m < 2; ++m)
        #pragma unroll
        for (int nt = 0; nt < 4; ++nt)
          acc1[m][nt] = __builtin_amdgcn_mfma_f32_16x16x32_f16(w1f[nt][kit], a[m], acc1[m][nt], 0, 0, 0);
    }

    // bias + SiLU, pack 4 consecutive hcols -> ds_write_b64
    #pragma unroll
    for (int m = 0; m < 2; ++m) {
      const int token = m * 16 + l16;
      #pragma unroll
      for (int nt = 0; nt < 4; ++nt) {
        f16x4 h;
        #pragma unroll
        for (int r = 0; r < 4; ++r) {
          const float z = acc1[m][nt][r] + b1v[nt][r];
          const float hv = z * __builtin_amdgcn_rcpf(1.0f + __expf(-z));
          h[r] = (_Float16)hv;
        }
        int byte = token * 512 + w * 128 + nt * 32 + lk * 8;
        byte ^= (token & 7) << 4;
        *(f16x4*)((char*)Hs + byte) = h;
      }
    }
    __syncthreads();

    // ---- prefetch X(st+1) while GEMM2 computes (T14) ----
    if (st + 1 < NST) {
      const float* Xp = Xbase + (size_t)(st + 1) * BT * DI;
      #pragma unroll
      for (int i = 0; i < 4; ++i)
        xr[i] = *(const float4*)(Xp + (size_t)(i * 256 + tid) * 4);
    }

    // ---- GEMM2 (swapped): D = W2tile^T * H^T ----
    f32x4 acc2[2][2];
    #pragma unroll
    for (int m = 0; m < 2; ++m)
      #pragma unroll
      for (int nt = 0; nt < 2; ++nt) acc2[m][nt] = (f32x4){0.f, 0.f, 0.f, 0.f};

    #pragma unroll
    for (int kit = 0; kit < 8; ++kit) {
      f16x8 hf[2];
      #pragma unroll
      for (int m = 0; m < 2; ++m) {
        const int token = m * 16 + l16;
        int byte = token * 512 + kit * 64 + lk * 16;
        byte ^= (token & 7) << 4;
        hf[m] = *(const f16x8*)((const char*)Hs + byte);
      }
      #pragma unroll
      for (int m = 0; m < 2; ++m)
        #pragma unroll
        for (int nt = 0; nt < 2; ++nt)
          acc2[m][nt] = __builtin_amdgcn_mfma_f32_16x16x32_f16(w2f[nt][kit], hf[m], acc2[m][nt], 0, 0, 0);
    }

    // epilogue: +b2, full-line coalesced dwordx4 stores (lane&15 = token row)
    float* Op = Obase + (size_t)st * BT * DO;
    #pragma unroll
    for (int m = 0; m < 2; ++m) {
      const int row = m * 16 + l16;
      #pragma unroll
      for (int nt = 0; nt < 2; ++nt) {
        const f32x4 o = acc2[m][nt] + b2v[nt];
        *(f32x4*)(Op + (size_t)row * DO + w * 32 + nt * 16 + lk * 4) = o;
      }
    }
  }
}

extern "C" void kernel_launch(void* const* d_in, const int* in_sizes, int n_in,
                              void* d_out, int out_size, void* d_ws, size_t ws_size,
                              hipStream_t stream) {
  const float* X  = (const float*)d_in[0];
  const float* W1 = (const float*)d_in[1];
  const float* B1 = (const float*)d_in[2];
  const float* W2 = (const float*)d_in[3];
  const float* B2 = (const float*)d_in[4];
  float* OUT = (float*)d_out;

  pmlp_kernel<<<dim3(512), dim3(256), 0, stream>>>(X, W1, B1, W2, B2, OUT);
}

// Round 4
// 295.739 us; speedup vs baseline: 1.7500x; 1.2905x over previous
//
#include <hip/hip_runtime.h>
#include <hip/hip_fp16.h>

#define N_INST 64
#define T_DIM  4096
#define DI     128
#define DH     256
#define DO     128
#define RPB    512          // tokens per block
#define BT     32           // tokens per subtile
#define NST    (RPB / BT)   // 16 subtiles
#define WELT   32768        // weight elements per instance per matrix

typedef _Float16 f16x8 __attribute__((ext_vector_type(8)));
typedef _Float16 f16x4 __attribute__((ext_vector_type(4)));
typedef float    f32x4 __attribute__((ext_vector_type(4)));

// ---------------- pre-kernel: repack fp32 weights -> fp16 MFMA fragments ----------------
// ws layout: [0, 64*32768)           : W1 frags [n][w(8)][nt(2)][kit(4)][lane(64)][j(8)]
//            [64*32768, 2*64*32768)  : W2 frags [n][w(8)][kit(8)][lane(64)][j(8)]
// Each 256-thread block reads full 64B sectors and writes 512B coalesced.
__global__ __launch_bounds__(256)
void repack_kernel(const float* __restrict__ W1, const float* __restrict__ W2,
                   _Float16* __restrict__ ws) {
  const int e = blockIdx.x * 256 + threadIdx.x;   // [0, 64*32768)
  {
    const int j    = e & 7;
    const int lane = (e >> 3) & 63;
    const int kit  = (e >> 9) & 3;
    const int nt   = (e >> 11) & 1;
    const int w    = (e >> 12) & 7;
    const int n    = e >> 15;
    const int k = kit * 32 + (lane >> 4) * 8 + j;
    const int h = w * 32 + nt * 16 + (lane & 15);
    ws[e] = (_Float16)W1[((size_t)n * DI + k) * DH + h];
  }
  {
    const int j    = e & 7;
    const int lane = (e >> 3) & 63;
    const int kit  = (e >> 9) & 7;
    const int w    = (e >> 12) & 7;
    const int n    = e >> 15;
    const int k = kit * 32 + (lane >> 4) * 8 + j;
    const int o = w * 16 + (lane & 15);
    ws[(size_t)N_INST * WELT + e] = (_Float16)W2[((size_t)n * DH + k) * DO + o];
  }
}

// ---------------- main fused kernel ----------------
// 512 blocks x 512 thr (8 waves). Instance n pinned to XCD n%8 (bid%8 heuristic).
// Wave w: GEMM1 hcols [32w,32w+32), GEMM2 ocols [16w,16w+16). Weights in regs
// (64 VGPR/wave, direct fragment loads from ws). X staged fp16 in swizzled LDS;
// H in swizzled LDS; OUT bounced through LDS for full-line nontemporal stores.
__global__ __launch_bounds__(512, 4)
void pmlp_kernel(const float* __restrict__ X, const _Float16* __restrict__ ws,
                 const float* __restrict__ B1, const float* __restrict__ B2,
                 float* __restrict__ OUT) {
  __shared__ __align__(16) char smem[24576];
  // [0,8192): Xs fp16 [32 tok][128 k], swizzled 256B rows
  // [8192,24576): Hs fp16 [32 tok][256 h] / Os fp32 [32 tok][128 o], swizzled 512B rows

  const int bid  = blockIdx.x;
  const int g    = bid & 7;             // XCD (round-robin heuristic)
  const int jj   = bid >> 3;
  const int n    = ((jj & 7) << 3) | g; // instance: n%8 == XCD
  const int row0 = (jj >> 3) * RPB;     // chunk 0..7

  const int tid = threadIdx.x;
  const int w   = tid >> 6;   // wave 0..7
  const int l   = tid & 63;
  const int l16 = l & 15;
  const int lk  = l >> 4;     // 0..3

  // ---- weight fragments: 16 coalesced 16B lane-loads ----
  f16x8 w1f[2][4], w2f[8];
  #pragma unroll
  for (int nt = 0; nt < 2; ++nt)
    #pragma unroll
    for (int kit = 0; kit < 4; ++kit)
      w1f[nt][kit] = *(const f16x8*)(ws + ((size_t)((n * 8 + w) * 8 + nt * 4 + kit) * 64 + l) * 8);
  const _Float16* ws2 = ws + (size_t)N_INST * WELT;
  #pragma unroll
  for (int kit = 0; kit < 8; ++kit)
    w2f[kit] = *(const f16x8*)(ws2 + ((size_t)((n * 8 + w) * 8 + kit) * 64 + l) * 8);

  f32x4 b1v[2], b2v;
  b1v[0] = *(const f32x4*)(B1 + n * DH + w * 32 + lk * 4);
  b1v[1] = *(const f32x4*)(B1 + n * DH + w * 32 + 16 + lk * 4);
  b2v    = *(const f32x4*)(B2 + n * DO + w * 16 + lk * 4);

  const float* Xbase = X + ((size_t)n * T_DIM + row0) * DI;
  float*       Obase = OUT + ((size_t)n * T_DIM + row0) * DO;

  // prologue: prefetch subtile 0 (2 x f32x4 per thread = whole 16KB subtile)
  f32x4 xr[2];
  #pragma unroll
  for (int i = 0; i < 2; ++i)
    xr[i] = __builtin_nontemporal_load((const f32x4*)Xbase + i * 512 + tid);

  #pragma unroll 1
  for (int st = 0; st < NST; ++st) {
    // ---- Xs(st) from prefetch regs (fp32->fp16, swizzled) ----
    #pragma unroll
    for (int i = 0; i < 2; ++i) {
      const int f4 = i * 512 + tid;
      const int r = f4 >> 5, c4 = f4 & 31;
      f16x4 hh;
      hh[0] = (_Float16)xr[i][0]; hh[1] = (_Float16)xr[i][1];
      hh[2] = (_Float16)xr[i][2]; hh[3] = (_Float16)xr[i][3];
      int byte = r * 256 + c4 * 8;
      byte ^= (r & 7) << 4;
      *(f16x4*)(smem + byte) = hh;
    }
    __syncthreads();

    // ---- issue next subtile's loads now; in flight across GEMM1+GEMM2 ----
    if (st + 1 < NST) {
      const f32x4* Xp = (const f32x4*)(Xbase + (size_t)(st + 1) * BT * DI);
      #pragma unroll
      for (int i = 0; i < 2; ++i)
        xr[i] = __builtin_nontemporal_load(Xp + i * 512 + tid);
    }

    // ---- GEMM1: acc1 = W1_tile^T * X^T (cols = tokens) ----
    f32x4 acc1[2][2] = {};
    #pragma unroll
    for (int kit = 0; kit < 4; ++kit) {
      f16x8 a[2];
      #pragma unroll
      for (int m = 0; m < 2; ++m) {
        const int r = m * 16 + l16;
        int byte = r * 256 + kit * 64 + lk * 16;
        byte ^= (r & 7) << 4;
        a[m] = *(const f16x8*)(smem + byte);
      }
      #pragma unroll
      for (int m = 0; m < 2; ++m)
        #pragma unroll
        for (int nt = 0; nt < 2; ++nt)
          acc1[m][nt] = __builtin_amdgcn_mfma_f32_16x16x32_f16(w1f[nt][kit], a[m], acc1[m][nt], 0, 0, 0);
    }

    // ---- bias + SiLU -> Hs (f16x4 ds_write_b64, swizzled) ----
    #pragma unroll
    for (int m = 0; m < 2; ++m) {
      const int token = m * 16 + l16;
      #pragma unroll
      for (int nt = 0; nt < 2; ++nt) {
        f16x4 hh;
        #pragma unroll
        for (int r = 0; r < 4; ++r) {
          const float z = acc1[m][nt][r] + b1v[nt][r];
          hh[r] = (_Float16)(z / (1.0f + __expf(-z)));
        }
        int byte = token * 512 + w * 64 + nt * 32 + lk * 8;
        byte ^= (token & 7) << 4;
        *(f16x4*)(smem + 8192 + byte) = hh;
      }
    }
    __syncthreads();

    // ---- GEMM2: acc2 = W2_tile^T * H^T ----
    f32x4 acc2[2] = {};
    #pragma unroll
    for (int kit = 0; kit < 8; ++kit) {
      f16x8 hf[2];
      #pragma unroll
      for (int m = 0; m < 2; ++m) {
        const int token = m * 16 + l16;
        int byte = token * 512 + kit * 64 + lk * 16;
        byte ^= (token & 7) << 4;
        hf[m] = *(const f16x8*)(smem + 8192 + byte);
      }
      #pragma unroll
      for (int m = 0; m < 2; ++m)
        acc2[m] = __builtin_amdgcn_mfma_f32_16x16x32_f16(w2f[kit], hf[m], acc2[m], 0, 0, 0);
    }
    __syncthreads();  // Hs reads done before Os overwrites the region

    // ---- Os = acc2 + b2 into LDS (fp32, swizzled) ----
    #pragma unroll
    for (int m = 0; m < 2; ++m) {
      const int token = m * 16 + l16;
      int byte = token * 512 + w * 64 + lk * 16;
      byte ^= (token & 7) << 4;
      *(f32x4*)(smem + 8192 + byte) = acc2[m] + b2v;
    }
    __syncthreads();

    // ---- full-line nontemporal OUT stores (lane-consecutive dwordx4) ----
    float* Op = Obase + (size_t)st * BT * DO;
    #pragma unroll
    for (int i = 0; i < 2; ++i) {
      const int f4 = i * 512 + tid;
      const int token = f4 >> 5;
      int byte = f4 * 16;
      byte ^= (token & 7) << 4;
      const f32x4 v = *(const f32x4*)(smem + 8192 + byte);
      __builtin_nontemporal_store(v, (f32x4*)Op + f4);
    }
  }
}

extern "C" void kernel_launch(void* const* d_in, const int* in_sizes, int n_in,
                              void* d_out, int out_size, void* d_ws, size_t ws_size,
                              hipStream_t stream) {
  const float* X  = (const float*)d_in[0];
  const float* W1 = (const float*)d_in[1];
  const float* B1 = (const float*)d_in[2];
  const float* W2 = (const float*)d_in[3];
  const float* B2 = (const float*)d_in[4];
  float* OUT = (float*)d_out;
  _Float16* wsp = (_Float16*)d_ws;  // needs 8.4 MB

  repack_kernel<<<dim3((N_INST * WELT) / 256), dim3(256), 0, stream>>>(W1, W2, wsp);
  pmlp_kernel<<<dim3(512), dim3(512), 0, stream>>>(X, wsp, B1, B2, OUT);
}